// Round 13
// baseline (1051.549 us; speedup 1.0000x reference)
//
#include <hip/hip_runtime.h>
#include <cstddef>

#define NN  100000
#define NE  600000
#define NG  4096
#define DIN 73
#define DE  101
#define DD  128
#define DD2 256
#define NP  100096   // NN padded to 64-row tiles
#define EP  600064   // NE padded to 128-row tiles (4688 tiles)

typedef unsigned int uint;
typedef unsigned short ushort;
typedef __attribute__((ext_vector_type(8))) short bf16x8;
typedef __attribute__((ext_vector_type(4))) float f32x4;

__device__ __forceinline__ void fadd_atomic(float* p, float v) { unsafeAtomicAdd(p, v); }

__device__ __forceinline__ ushort f2bf(float f) {   // RNE f32->bf16
    uint u = __float_as_uint(f);
    uint r = (u + 0x7fffu + ((u >> 16) & 1u)) >> 16;
    return (ushort)r;
}
__device__ __forceinline__ float bf2f(ushort u) { return __uint_as_float(((uint)u) << 16); }

// f32x8 -> bf16x8 fragment (for mlp1 reading f32 z)
__device__ __forceinline__ bf16x8 ld_zfrag(const float* __restrict__ p) {
    const float4 f0 = *(const float4*)p;
    const float4 f1 = *(const float4*)(p + 4);
    bf16x8 r;
    r[0] = (short)f2bf(f0.x); r[1] = (short)f2bf(f0.y);
    r[2] = (short)f2bf(f0.z); r[3] = (short)f2bf(f0.w);
    r[4] = (short)f2bf(f1.x); r[5] = (short)f2bf(f1.y);
    r[6] = (short)f2bf(f1.z); r[7] = (short)f2bf(f1.w);
    return r;
}

// LDS-only barrier: orders all LDS ops (lgkmcnt) across the workgroup but does
// NOT drain vmcnt -- fire-and-forget zf atomics stay in flight across tiles.
#define BARRIER_LDS() asm volatile("s_waitcnt lgkmcnt(0)\n\ts_barrier" ::: "memory")

// ---------------- CSR build (once per call) ---------------------------------

__global__ void hist_kernel(const int* __restrict__ dst, int* __restrict__ deg) {
    int e = blockIdx.x * blockDim.x + threadIdx.x;
    if (e < NE) atomicAdd(&deg[dst[e]], 1);
}

__global__ __launch_bounds__(256) void scan_chunk_kernel(
    const int* __restrict__ deg, int* __restrict__ offs, int* __restrict__ csums)
{
    const int b = blockIdx.x, t = threadIdx.x;
    const int base = b * 1024 + t * 4;
    int v[4];
    #pragma unroll
    for (int i = 0; i < 4; ++i) v[i] = (base + i < NN) ? deg[base + i] : 0;
    int tsum = v[0] + v[1] + v[2] + v[3];
    const int lane = t & 63, w = t >> 6;
    int x = tsum;
    #pragma unroll
    for (int d = 1; d < 64; d <<= 1) {
        int y = __shfl_up(x, d, 64);
        if (lane >= d) x += y;
    }
    __shared__ int wsum[4];
    if (lane == 63) wsum[w] = x;
    __syncthreads();
    int woff = 0;
    for (int i = 0; i < w; ++i) woff += wsum[i];
    int run = woff + x - tsum;
    #pragma unroll
    for (int i = 0; i < 4; ++i) {
        if (base + i < NN) offs[base + i] = run;
        run += v[i];
    }
    if (t == 255) csums[b] = woff + x;
}

__global__ void scan_tops_kernel(int* __restrict__ csums, int* __restrict__ offs, int nchunks) {
    if (threadIdx.x == 0 && blockIdx.x == 0) {
        int run = 0;
        for (int i = 0; i < nchunks; ++i) { int c = csums[i]; csums[i] = run; run += c; }
        offs[NN] = run;
    }
}

__global__ void scan_add_kernel(int* __restrict__ offs, const int* __restrict__ csums) {
    int i = blockIdx.x * blockDim.x + threadIdx.x;
    if (i < NN) offs[i] += csums[i >> 10];
}

// builds eperm (edge -> csr position), srcp and dstp (csr-ordered src/dst)
__global__ void scatter_kernel(const int* __restrict__ dst, const int* __restrict__ src,
                               const int* __restrict__ offs, int* __restrict__ cursor,
                               int* __restrict__ eperm, int* __restrict__ srcp,
                               int* __restrict__ dstp)
{
    int e = blockIdx.x * blockDim.x + threadIdx.x;
    if (e >= NE) return;
    int d = dst[e];
    int pos = offs[d] + atomicAdd(&cursor[d], 1);
    eperm[e] = pos;
    srcp[pos] = src[e];
    dstp[pos] = d;
}

__global__ void gstart_kernel(const int* __restrict__ batch, int* __restrict__ gstart) {
    int n = blockIdx.x * blockDim.x + threadIdx.x;
    if (n > NN) return;
    if (n == NN) {
        for (int g = batch[NN - 1] + 1; g <= NG; ++g) gstart[g] = NN;
        return;
    }
    int b = batch[n];
    int pb = (n == 0) ? -1 : batch[n - 1];
    for (int g = pb + 1; g <= b; ++g) gstart[g] = n;
}

// ---------------- conversions ----------------------------------------------

// ea f32 [E,101] -> bf16 [EP,128] in CSR order; col 101 = 1.0 (bias slot)
__global__ __launch_bounds__(256) void cvt_ea_kernel(const float* __restrict__ ea,
                                                     const int* __restrict__ eperm,
                                                     ushort* __restrict__ eabc)
{
    const int t = threadIdx.x;
    const int r = blockIdx.x * 8 + (t >> 5);
    if (r >= NE) return;
    const int pos = eperm[r];
    const int c = (t & 31) * 4;
    ushort4 o;
    #pragma unroll
    for (int i = 0; i < 4; ++i) {
        const int col = c + i;
        float v = (col < DE) ? ea[(size_t)r * DE + col] : ((col == DE) ? 1.0f : 0.0f);
        ((ushort*)&o)[i] = f2bf(v);
    }
    *(ushort4*)&eabc[(size_t)pos * 128 + c] = o;
}

// in f32 [Kin,Nn] -> out bf16 [Nn][Kp] transposed; row Kin = bias (if given), rest 0
__global__ void cvt_wt_kernel(const float* __restrict__ in, ushort* __restrict__ out,
                              int Kin, int Nn, int Kp, const float* __restrict__ bias)
{
    const int n = blockIdx.x;
    for (int k = threadIdx.x; k < Kp; k += blockDim.x) {
        float v = 0.0f;
        if (k < Kin) v = in[(size_t)k * Nn + n];
        else if (k == Kin && bias) v = bias[n];
        out[(size_t)n * Kp + k] = f2bf(v);
    }
}

// ---------------- fused edge GEMM + segment-sum aggregation ------------------
// Round-11 structure + ONE change: the h[srcp] gather for tile t+1 is issued
// BEFORE the reduce phase of tile t (T14 issue-early/consume-late), so the
// ~500-cycle L3 gather latency hides under the ~600-cycle serial reduce
// instead of stalling the epilogue.
__global__ __launch_bounds__(256, 2) void edge_agg_kernel(
    const ushort* __restrict__ eab, const ushort* __restrict__ Wt,
    const int* __restrict__ srcp, const int* __restrict__ dstp,
    const ushort* __restrict__ hb, float* __restrict__ zf)
{
    __shared__ ushort vals[128 * 128];   // [row][col], col XOR-swizzled by row
    __shared__ int nd[128];              // dst node per tile row
    const int tid = threadIdx.x;
    const int wid = tid >> 6;
    const int msub = wid >> 1, nsl = wid & 1;
    const int lane = tid & 63, l15 = lane & 15, grp = lane >> 4;
    const int n0 = nsl * 64;

    bf16x8 A[4][4];
    #pragma unroll
    for (int nf = 0; nf < 4; ++nf)
        #pragma unroll
        for (int kk = 0; kk < 4; ++kk)
            A[nf][kk] = *(const bf16x8*)(Wt + (size_t)(n0 + nf * 16 + l15) * 128 + kk * 32 + grp * 8);

    const int rcol = tid & 127;   // reduce-phase column
    const int rh   = tid >> 7;    // reduce-phase row half (0/1)

    const int ntiles = EP / 128;  // 4688

    // prologue: gather h for the first tile
    ushort4 hv[4][4];
    {
        const int t0 = blockIdx.x;
        if (t0 < ntiles) {
            #pragma unroll
            for (int mf = 0; mf < 4; ++mf) {
                const int rr = t0 * 128 + msub * 64 + mf * 16 + l15;
                const int sp = (rr < NE) ? srcp[rr] : 0;
                #pragma unroll
                for (int nf = 0; nf < 4; ++nf)
                    hv[mf][nf] = *(const ushort4*)&hb[(size_t)sp * 128 + n0 + nf * 16 + grp * 4];
            }
        }
    }

    for (int t = blockIdx.x; t < ntiles; t += gridDim.x) {
        const int r0 = t * 128;
        const int m0 = r0 + msub * 64;
        BARRIER_LDS();            // previous tile's reduce done before overwriting LDS
        if (tid < 128) {
            const int rr = r0 + tid;
            nd[tid] = (rr < NE) ? dstp[rr] : NN;
        }
        // GEMM
        f32x4 acc[4][4];
        #pragma unroll
        for (int i = 0; i < 4; ++i)
            #pragma unroll
            for (int j = 0; j < 4; ++j) acc[i][j] = (f32x4){0.f, 0.f, 0.f, 0.f};
        #pragma unroll
        for (int kk = 0; kk < 4; ++kk) {
            bf16x8 b[4];
            #pragma unroll
            for (int mf = 0; mf < 4; ++mf)
                b[mf] = *(const bf16x8*)(eab + (size_t)(m0 + mf * 16 + l15) * 128 + kk * 32 + grp * 8);
            #pragma unroll
            for (int mf = 0; mf < 4; ++mf)
                #pragma unroll
                for (int nf = 0; nf < 4; ++nf)
                    acc[mf][nf] = __builtin_amdgcn_mfma_f32_16x16x32_bf16(A[nf][kk], b[mf], acc[mf][nf], 0, 0, 0);
        }
        // relu(e + h) -> LDS (swizzled: ushort-index col ^ ((row&7)<<3))
        #pragma unroll
        for (int mf = 0; mf < 4; ++mf) {
            const int row = msub * 64 + mf * 16 + l15;
            const int sw = (row & 7) << 3;
            #pragma unroll
            for (int nf = 0; nf < 4; ++nf) {
                const int col = n0 + nf * 16 + grp * 4;
                ushort4 o;
                o.x = f2bf(fmaxf(acc[mf][nf][0] + bf2f(hv[mf][nf].x), 0.f));
                o.y = f2bf(fmaxf(acc[mf][nf][1] + bf2f(hv[mf][nf].y), 0.f));
                o.z = f2bf(fmaxf(acc[mf][nf][2] + bf2f(hv[mf][nf].z), 0.f));
                o.w = f2bf(fmaxf(acc[mf][nf][3] + bf2f(hv[mf][nf].w), 0.f));
                *(ushort4*)&vals[row * 128 + (col ^ sw)] = o;
            }
        }
        BARRIER_LDS();
        // issue NEXT tile's h-gather now -- its latency hides under the reduce
        const int tn = t + gridDim.x;
        ushort4 hvn[4][4];
        if (tn < ntiles) {
            #pragma unroll
            for (int mf = 0; mf < 4; ++mf) {
                const int rr = tn * 128 + msub * 64 + mf * 16 + l15;
                const int sp = (rr < NE) ? srcp[rr] : 0;
                #pragma unroll
                for (int nf = 0; nf < 4; ++nf)
                    hvn[mf][nf] = *(const ushort4*)&hb[(size_t)sp * 128 + n0 + nf * 16 + grp * 4];
            }
        }
        // serial segment reduce down the tile (branches wave-uniform: rows shared)
        float accs = 0.f;
        int cur = nd[rh * 64];
        for (int r = rh * 64; r < rh * 64 + 64; ++r) {
            const int node = nd[r];
            const float v = bf2f(vals[r * 128 + (rcol ^ ((r & 7) << 3))]);
            if (node != cur) {
                if (cur < NN) fadd_atomic(&zf[(size_t)cur * 128 + rcol], accs);
                accs = 0.f; cur = node;
            }
            accs += v;
        }
        if (cur < NN) fadd_atomic(&zf[(size_t)cur * 128 + rcol], accs);
        // rotate prefetched gather into place
        if (tn < ntiles) {
            #pragma unroll
            for (int mf = 0; mf < 4; ++mf)
                #pragma unroll
                for (int nf = 0; nf < 4; ++nf)
                    hv[mf][nf] = hvn[mf][nf];
        }
    }
}

// ---------------- weight-stationary MFMA GEMMs ------------------------------

// mlp1: y1 = z@W1 + b1 -> bf16 [NP,256]; z is f32, converted in-register.
// BN column stats accumulated in registers, flushed once per block.
__global__ __launch_bounds__(256, 2) void mlp1_gemm_kernel(
    const float* __restrict__ z, const ushort* __restrict__ Wt,
    const float* __restrict__ bias, ushort* __restrict__ y,
    float* __restrict__ s1, float* __restrict__ sq1)
{
    const int n0 = (threadIdx.x >> 6) * 64;
    const int lane = threadIdx.x & 63, l15 = lane & 15, grp = lane >> 4;
    bf16x8 A[4][4];
    #pragma unroll
    for (int nf = 0; nf < 4; ++nf)
        #pragma unroll
        for (int kk = 0; kk < 4; ++kk)
            A[nf][kk] = *(const bf16x8*)(Wt + (size_t)(n0 + nf * 16 + l15) * 128 + kk * 32 + grp * 8);
    float4 bv[4];
    #pragma unroll
    for (int nf = 0; nf < 4; ++nf) bv[nf] = *(const float4*)&bias[n0 + nf * 16 + grp * 4];

    float sj[4][4] = {}, qj[4][4] = {};

    const int ntiles = NP / 64;   // 1564
    for (int t = blockIdx.x; t < ntiles; t += gridDim.x) {
        const int m0 = t * 64;
        f32x4 acc[4][4];
        #pragma unroll
        for (int i = 0; i < 4; ++i)
            #pragma unroll
            for (int j = 0; j < 4; ++j) acc[i][j] = (f32x4){0.f, 0.f, 0.f, 0.f};
        #pragma unroll
        for (int kk = 0; kk < 4; ++kk) {
            bf16x8 b[4];
            #pragma unroll
            for (int mf = 0; mf < 4; ++mf)
                b[mf] = ld_zfrag(z + (size_t)(m0 + mf * 16 + l15) * 128 + kk * 32 + grp * 8);
            #pragma unroll
            for (int mf = 0; mf < 4; ++mf)
                #pragma unroll
                for (int nf = 0; nf < 4; ++nf)
                    acc[mf][nf] = __builtin_amdgcn_mfma_f32_16x16x32_bf16(A[nf][kk], b[mf], acc[mf][nf], 0, 0, 0);
        }
        #pragma unroll
        for (int mf = 0; mf < 4; ++mf) {
            const int m = m0 + mf * 16 + l15;
            const bool valid = m < NN;
            ushort* rp = &y[(size_t)m * 256 + n0];
            #pragma unroll
            for (int nf = 0; nf < 4; ++nf) {
                ushort4 o;
                o.x = f2bf(acc[mf][nf][0] + bv[nf].x);
                o.y = f2bf(acc[mf][nf][1] + bv[nf].y);
                o.z = f2bf(acc[mf][nf][2] + bv[nf].z);
                o.w = f2bf(acc[mf][nf][3] + bv[nf].w);
                *(ushort4*)&rp[nf * 16 + grp * 4] = o;
                if (valid) {
                    float v0 = bf2f(o.x), v1 = bf2f(o.y), v2 = bf2f(o.z), v3 = bf2f(o.w);
                    sj[nf][0] += v0; qj[nf][0] += v0 * v0;
                    sj[nf][1] += v1; qj[nf][1] += v1 * v1;
                    sj[nf][2] += v2; qj[nf][2] += v2 * v2;
                    sj[nf][3] += v3; qj[nf][3] += v3 * v3;
                }
            }
        }
    }
    #pragma unroll
    for (int nf = 0; nf < 4; ++nf) {
        #pragma unroll
        for (int j = 0; j < 4; ++j) {
            float s = sj[nf][j], q = qj[nf][j];
            #pragma unroll
            for (int off = 1; off < 16; off <<= 1) {
                s += __shfl_xor(s, off, 16);
                q += __shfl_xor(q, off, 16);
            }
            if (l15 == 0) {
                const int col = n0 + nf * 16 + grp * 4 + j;
                fadd_atomic(&s1[col], s);
                fadd_atomic(&sq1[col], q);
            }
        }
    }
}

// mlp2: y2 = y1r@W2 + b2 -> bf16 [NP,128]  (y1r pre-activated in place), K=256
__global__ __launch_bounds__(256, 2) void mlp2_gemm_kernel(
    const ushort* __restrict__ y1, const ushort* __restrict__ Wt,
    const float* __restrict__ bias, ushort* __restrict__ y2)
{
    const int wid = threadIdx.x >> 6;
    const int msub = wid >> 1, nsl = wid & 1;
    const int lane = threadIdx.x & 63, l15 = lane & 15, grp = lane >> 4;
    const int n0 = nsl * 64;
    bf16x8 A[4][8];
    #pragma unroll
    for (int nf = 0; nf < 4; ++nf)
        #pragma unroll
        for (int kk = 0; kk < 8; ++kk)
            A[nf][kk] = *(const bf16x8*)(Wt + (size_t)(n0 + nf * 16 + l15) * 256 + kk * 32 + grp * 8);
    float4 bv[4];
    #pragma unroll
    for (int nf = 0; nf < 4; ++nf) bv[nf] = *(const float4*)&bias[n0 + nf * 16 + grp * 4];

    const int ntiles = NP / 128;   // 782
    for (int t = blockIdx.x; t < ntiles; t += gridDim.x) {
        const int m0 = t * 128 + msub * 64;
        f32x4 acc[4][4];
        #pragma unroll
        for (int i = 0; i < 4; ++i)
            #pragma unroll
            for (int j = 0; j < 4; ++j) acc[i][j] = (f32x4){0.f, 0.f, 0.f, 0.f};
        #pragma unroll
        for (int kk = 0; kk < 8; ++kk) {
            bf16x8 b[4];
            #pragma unroll
            for (int mf = 0; mf < 4; ++mf)
                b[mf] = *(const bf16x8*)(y1 + (size_t)(m0 + mf * 16 + l15) * 256 + kk * 32 + grp * 8);
            #pragma unroll
            for (int mf = 0; mf < 4; ++mf)
                #pragma unroll
                for (int nf = 0; nf < 4; ++nf)
                    acc[mf][nf] = __builtin_amdgcn_mfma_f32_16x16x32_bf16(A[nf][kk], b[mf], acc[mf][nf], 0, 0, 0);
        }
        #pragma unroll
        for (int mf = 0; mf < 4; ++mf) {
            ushort* rp = &y2[(size_t)(m0 + mf * 16 + l15) * 128 + n0];
            #pragma unroll
            for (int nf = 0; nf < 4; ++nf) {
                ushort4 o;
                o.x = f2bf(acc[mf][nf][0] + bv[nf].x);
                o.y = f2bf(acc[mf][nf][1] + bv[nf].y);
                o.z = f2bf(acc[mf][nf][2] + bv[nf].z);
                o.w = f2bf(acc[mf][nf][3] + bv[nf].w);
                *(ushort4*)&rp[nf * 16 + grp * 4] = o;
            }
        }
    }
}

// ---------------- elementwise / stats kernels --------------------------------

// h = bf16(x @ W_emb + b_emb); also zf = f32(h)  (runs once; replaces zinit)
__global__ __launch_bounds__(128) void embed_kernel(
    const float* __restrict__ x, const float* __restrict__ W,
    const float* __restrict__ b, ushort* __restrict__ hb, float* __restrict__ zf)
{
    __shared__ float xs[4][DIN];
    const int n0 = blockIdx.x * 4;
    const int d  = threadIdx.x;
    for (int idx = d; idx < 4 * DIN; idx += 128) {
        int r = idx / DIN, c = idx - r * DIN;
        xs[r][c] = x[(size_t)n0 * DIN + idx];
    }
    __syncthreads();
    float bb = b[d];
    float a0 = bb, a1 = bb, a2 = bb, a3 = bb;
    for (int k = 0; k < DIN; ++k) {
        float w = W[k * DD + d];
        a0 = fmaf(xs[0][k], w, a0);
        a1 = fmaf(xs[1][k], w, a1);
        a2 = fmaf(xs[2][k], w, a2);
        a3 = fmaf(xs[3][k], w, a3);
    }
    ushort u0 = f2bf(a0), u1 = f2bf(a1), u2 = f2bf(a2), u3 = f2bf(a3);
    hb[(size_t)(n0 + 0) * DD + d] = u0;
    hb[(size_t)(n0 + 1) * DD + d] = u1;
    hb[(size_t)(n0 + 2) * DD + d] = u2;
    hb[(size_t)(n0 + 3) * DD + d] = u3;
    zf[(size_t)(n0 + 0) * DD + d] = bf2f(u0);
    zf[(size_t)(n0 + 1) * DD + d] = bf2f(u1);
    zf[(size_t)(n0 + 2) * DD + d] = bf2f(u2);
    zf[(size_t)(n0 + 3) * DD + d] = bf2f(u3);
}

// column sums/sumsq of bf16 [*,128], rows < NN
__global__ __launch_bounds__(256) void colstats128b_kernel(
    const ushort* __restrict__ y, float* __restrict__ s, float* __restrict__ q)
{
    const int t = threadIdx.x;
    const int cs = (t & 31) * 4, rg = t >> 5;
    const int r0 = blockIdx.x * 256;
    float ps0 = 0, ps1 = 0, ps2 = 0, ps3 = 0, pq0 = 0, pq1 = 0, pq2 = 0, pq3 = 0;
    for (int i = rg; i < 256; i += 8) {
        const int r = r0 + i;
        if (r >= NN) break;
        ushort4 u = *(const ushort4*)&y[(size_t)r * 128 + cs];
        float f0 = bf2f(u.x), f1 = bf2f(u.y), f2v = bf2f(u.z), f3 = bf2f(u.w);
        ps0 += f0; pq0 += f0 * f0;
        ps1 += f1; pq1 += f1 * f1;
        ps2 += f2v; pq2 += f2v * f2v;
        ps3 += f3; pq3 += f3 * f3;
    }
    __shared__ float SS[8][128], SQ[8][128];
    SS[rg][cs + 0] = ps0; SS[rg][cs + 1] = ps1; SS[rg][cs + 2] = ps2; SS[rg][cs + 3] = ps3;
    SQ[rg][cs + 0] = pq0; SQ[rg][cs + 1] = pq1; SQ[rg][cs + 2] = pq2; SQ[rg][cs + 3] = pq3;
    __syncthreads();
    if (rg == 0) {
        #pragma unroll
        for (int j = 0; j < 4; ++j) {
            const int c = cs + j;
            float sv = 0, qv = 0;
            #pragma unroll
            for (int g = 0; g < 8; ++g) { sv += SS[g][c]; qv += SQ[g][c]; }
            fadd_atomic(&s[c], sv);
            fadd_atomic(&q[c], qv);
        }
    }
}

__global__ void finalize_kernel(const float* __restrict__ s, const float* __restrict__ sq,
                                const float* __restrict__ g, const float* __restrict__ bb,
                                float* __restrict__ a, float* __restrict__ c,
                                int dim, float invN)
{
    int d = blockIdx.x * blockDim.x + threadIdx.x;
    if (d >= dim) return;
    float m  = s[d] * invN;
    float v  = sq[d] * invN - m * m;
    float rs = rsqrtf(v + 1e-5f);
    float ai = g[d] * rs;
    a[d] = ai;
    c[d] = bb[d] - m * ai;
}

// y1 = bf16(relu(bn1(y1))) in place, rows < NN  (256 cols)
__global__ void bnrelu_bf_kernel(ushort* __restrict__ y, const float* __restrict__ a,
                                 const float* __restrict__ c)
{
    int i = blockIdx.x * blockDim.x + threadIdx.x;
    const int stride = gridDim.x * blockDim.x;
    for (; i < NN * 64; i += stride) {
        const int cb = (i & 63) * 4;
        ushort4 u = *(const ushort4*)&y[(size_t)i * 4];
        const float4 av = *(const float4*)&a[cb];
        const float4 cv = *(const float4*)&c[cb];
        ushort4 o;
        o.x = f2bf(fmaxf(fmaf(bf2f(u.x), av.x, cv.x), 0.f));
        o.y = f2bf(fmaxf(fmaf(bf2f(u.y), av.y, cv.y), 0.f));
        o.z = f2bf(fmaxf(fmaf(bf2f(u.z), av.z, cv.z), 0.f));
        o.w = f2bf(fmaxf(fmaf(bf2f(u.w), av.w, cv.w), 0.f));
        *(ushort4*)&y[(size_t)i * 4] = o;
    }
}

// h = bf16(relu(bn(y2))) in place; also zf = f32(h)  (layer 0; replaces zinit)
__global__ void bnrelu_hb_kernel(ushort* __restrict__ hb, const float* __restrict__ a,
                                 const float* __restrict__ c, float* __restrict__ zf)
{
    int i = blockIdx.x * blockDim.x + threadIdx.x;
    const int stride = gridDim.x * blockDim.x;
    for (; i < NN * 32; i += stride) {
        const int cb = (i & 31) * 4;
        ushort4 u = *(const ushort4*)&hb[(size_t)i * 4];
        const float4 av = *(const float4*)&a[cb];
        const float4 cv = *(const float4*)&c[cb];
        ushort4 o;
        o.x = f2bf(fmaxf(fmaf(bf2f(u.x), av.x, cv.x), 0.f));
        o.y = f2bf(fmaxf(fmaf(bf2f(u.y), av.y, cv.y), 0.f));
        o.z = f2bf(fmaxf(fmaf(bf2f(u.z), av.z, cv.z), 0.f));
        o.w = f2bf(fmaxf(fmaf(bf2f(u.w), av.w, cv.w), 0.f));
        *(ushort4*)&hb[(size_t)i * 4] = o;
        float4 zo;
        zo.x = bf2f(o.x); zo.y = bf2f(o.y); zo.z = bf2f(o.z); zo.w = bf2f(o.w);
        *(float4*)&zf[(size_t)i * 4] = zo;
    }
}

// final: out[g] = bn(mean over node range of y2)  (one wave per graph)
__global__ __launch_bounds__(256) void pool_kernel(
    const ushort* __restrict__ hb, const float* __restrict__ a2, const float* __restrict__ c2,
    const int* __restrict__ gstart, float* __restrict__ out)
{
    const int g = blockIdx.x * 4 + (threadIdx.x >> 6);
    if (g >= NG) return;
    const int lane = threadIdx.x & 63;
    const int s = gstart[g], t = gstart[g + 1];
    float a0 = 0.f, a1 = 0.f;
    for (int n = s; n < t; ++n) {
        const uint v = *(const uint*)&hb[(size_t)n * 128 + lane * 2];
        a0 += __uint_as_float(v << 16);
        a1 += __uint_as_float(v & 0xffff0000u);
    }
    const int d0 = lane * 2;
    float2 o;
    if (t > s) {
        const float inv = 1.0f / (float)(t - s);
        o.x = fmaf(a2[d0 + 0], a0 * inv, c2[d0 + 0]);
        o.y = fmaf(a2[d0 + 1], a1 * inv, c2[d0 + 1]);
    } else {
        o.x = 0.f; o.y = 0.f;
    }
    *(float2*)&out[(size_t)g * 128 + d0] = o;
}

// ---------------- launch ----------------------------------------------------

extern "C" void kernel_launch(void* const* d_in, const int* in_sizes, int n_in,
                              void* d_out, int out_size, void* d_ws, size_t ws_size,
                              hipStream_t stream)
{
    (void)in_sizes; (void)n_in; (void)out_size; (void)ws_size;
    const float* x     = (const float*)d_in[0];
    const float* ea    = (const float*)d_in[1];
    const int*   src   = (const int*)d_in[2];
    const int*   dst   = (const int*)d_in[3];
    const int*   batch = (const int*)d_in[4];
    const float* W_emb = (const float*)d_in[5];
    const float* b_emb = (const float*)d_in[6];

    char* ws = (char*)d_ws;
    auto alloc = [&](size_t bytes) { void* p = ws; ws += (bytes + 255) & ~(size_t)255; return p; };

    ushort* hb   = (ushort*)alloc((size_t)NP * 128 * 2);   // 25.6 MB  h / y2 (bf16)
    float*  zf   = (float*) alloc((size_t)NP * 128 * 4);   // 51.2 MB  z (f32)
    ushort* eabc = (ushort*)alloc((size_t)EP * 128 * 2);   // 153.6 MB ea bf16, CSR order
    ushort* y1b  = (ushort*)alloc((size_t)NP * 256 * 2);   // 51.2 MB  y1 (bf16)
    int* deg    = (int*)alloc((size_t)NN * 4);
    int* offs   = (int*)alloc((size_t)(NN + 1) * 4);
    int* eperm  = (int*)alloc((size_t)NE * 4);
    int* srcp   = (int*)alloc((size_t)NE * 4);
    int* dstp   = (int*)alloc((size_t)NE * 4);
    int* csums  = (int*)alloc(128 * 4);
    int* gstart = (int*)alloc((size_t)(NG + 1) * 4);
    ushort* Wet[2], *W1t[2], *W2t[2];
    for (int l = 0; l < 2; ++l) {
        Wet[l] = (ushort*)alloc(128 * 128 * 2);
        W1t[l] = (ushort*)alloc(256 * 128 * 2);
        W2t[l] = (ushort*)alloc(128 * 256 * 2);
    }
    float* st = (float*)alloc(2048 * 4);
    float* s1 = st,        *sq1 = st + 256, *a1 = st + 512,  *c1 = st + 768;
    float* s2 = st + 1024, *sq2 = st + 1152, *a2 = st + 1280, *c2 = st + 1408;
    float* out = (float*)d_out;

    const int NCHUNK = (NN + 1023) / 1024;

    // CSR + permutation + graph boundaries (constant across layers)
    hipMemsetAsync(deg, 0, (size_t)NN * 4, stream);
    hist_kernel<<<(NE + 255) / 256, 256, 0, stream>>>(dst, deg);
    scan_chunk_kernel<<<NCHUNK, 256, 0, stream>>>(deg, offs, csums);
    scan_tops_kernel<<<1, 1, 0, stream>>>(csums, offs, NCHUNK);
    scan_add_kernel<<<(NN + 255) / 256, 256, 0, stream>>>(offs, csums);
    hipMemsetAsync(deg, 0, (size_t)NN * 4, stream);
    scatter_kernel<<<(NE + 255) / 256, 256, 0, stream>>>(dst, src, offs, deg, eperm, srcp, dstp);
    gstart_kernel<<<(NN + 256) / 256, 256, 0, stream>>>(batch, gstart);

    // one-time conversions (ea goes directly to CSR order, bias slot at col 101)
    cvt_ea_kernel<<<(NE + 7) / 8, 256, 0, stream>>>(ea, eperm, eabc);
    for (int l = 0; l < 2; ++l) {
        const float* const* L = (const float* const*)(d_in + 7 + l * 10);
        cvt_wt_kernel<<<128, 128, 0, stream>>>(L[0], Wet[l], 101, 128, 128, L[1]);  // We + be row
        cvt_wt_kernel<<<256, 128, 0, stream>>>(L[2], W1t[l], 128, 256, 128, nullptr);
        cvt_wt_kernel<<<128, 128, 0, stream>>>(L[6], W2t[l], 256, 128, 256, nullptr);
    }

    embed_kernel<<<NN / 4, 128, 0, stream>>>(x, W_emb, b_emb, hb, zf);

    for (int layer = 0; layer < 2; ++layer) {
        const float* const* L = (const float* const*)(d_in + 7 + layer * 10);
        const float* b1  = L[3];
        const float* g1  = L[4]; const float* bb1 = L[5];
        const float* b2  = L[7];
        const float* go  = L[8]; const float* bo  = L[9];

        hipMemsetAsync(s1, 0, 512 * sizeof(float), stream);   // s1+sq1
        hipMemsetAsync(s2, 0, 256 * sizeof(float), stream);   // s2+sq2

        edge_agg_kernel<<<1172, 256, 0, stream>>>(eabc, Wet[layer], srcp, dstp, hb, zf);

        mlp1_gemm_kernel<<<782, 256, 0, stream>>>(zf, W1t[layer], b1, y1b, s1, sq1);
        finalize_kernel<<<1, 256, 0, stream>>>(s1, sq1, g1, bb1, a1, c1, 256, 1.0f / NN);
        bnrelu_bf_kernel<<<2048, 256, 0, stream>>>(y1b, a1, c1);
        mlp2_gemm_kernel<<<391, 256, 0, stream>>>(y1b, W2t[layer], b2, hb);
        colstats128b_kernel<<<NP / 256 + 1, 256, 0, stream>>>(hb, s2, sq2);
        finalize_kernel<<<1, 128, 0, stream>>>(s2, sq2, go, bo, a2, c2, 128, 1.0f / NN);

        if (layer == 0) {
            bnrelu_hb_kernel<<<2048, 256, 0, stream>>>(hb, a2, c2, zf);
        } else {
            pool_kernel<<<NG / 4, 256, 0, stream>>>(hb, a2, c2, gstart, out);
        }
    }
}

// Round 14
// 1032.565 us; speedup vs baseline: 1.0184x; 1.0184x over previous
//
#include <hip/hip_runtime.h>
#include <cstddef>

#define NN  100000
#define NE  600000
#define NG  4096
#define DIN 73
#define DE  101
#define DD  128
#define DD2 256
#define NP  100096   // NN padded to 64-row tiles
#define EP  600064   // NE padded to 128-row tiles (4688 tiles)

typedef unsigned int uint;
typedef unsigned short ushort;
typedef __attribute__((ext_vector_type(8))) short bf16x8;
typedef __attribute__((ext_vector_type(4))) float f32x4;

__device__ __forceinline__ void fadd_atomic(float* p, float v) { unsafeAtomicAdd(p, v); }

__device__ __forceinline__ ushort f2bf(float f) {   // RNE f32->bf16
    uint u = __float_as_uint(f);
    uint r = (u + 0x7fffu + ((u >> 16) & 1u)) >> 16;
    return (ushort)r;
}
__device__ __forceinline__ float bf2f(ushort u) { return __uint_as_float(((uint)u) << 16); }

// f32x8 -> bf16x8 fragment (for mlp1 reading f32 z)
__device__ __forceinline__ bf16x8 ld_zfrag(const float* __restrict__ p) {
    const float4 f0 = *(const float4*)p;
    const float4 f1 = *(const float4*)(p + 4);
    bf16x8 r;
    r[0] = (short)f2bf(f0.x); r[1] = (short)f2bf(f0.y);
    r[2] = (short)f2bf(f0.z); r[3] = (short)f2bf(f0.w);
    r[4] = (short)f2bf(f1.x); r[5] = (short)f2bf(f1.y);
    r[6] = (short)f2bf(f1.z); r[7] = (short)f2bf(f1.w);
    return r;
}

// LDS-only barrier: orders all LDS ops (lgkmcnt) across the workgroup but does
// NOT drain vmcnt -- fire-and-forget zf atomics stay in flight across tiles.
#define BARRIER_LDS() asm volatile("s_waitcnt lgkmcnt(0)\n\ts_barrier" ::: "memory")

// ---------------- CSR build (once per call) ---------------------------------

__global__ void hist_kernel(const int* __restrict__ dst, int* __restrict__ deg) {
    int e = blockIdx.x * blockDim.x + threadIdx.x;
    if (e < NE) atomicAdd(&deg[dst[e]], 1);
}

__global__ __launch_bounds__(256) void scan_chunk_kernel(
    const int* __restrict__ deg, int* __restrict__ offs, int* __restrict__ csums)
{
    const int b = blockIdx.x, t = threadIdx.x;
    const int base = b * 1024 + t * 4;
    int v[4];
    #pragma unroll
    for (int i = 0; i < 4; ++i) v[i] = (base + i < NN) ? deg[base + i] : 0;
    int tsum = v[0] + v[1] + v[2] + v[3];
    const int lane = t & 63, w = t >> 6;
    int x = tsum;
    #pragma unroll
    for (int d = 1; d < 64; d <<= 1) {
        int y = __shfl_up(x, d, 64);
        if (lane >= d) x += y;
    }
    __shared__ int wsum[4];
    if (lane == 63) wsum[w] = x;
    __syncthreads();
    int woff = 0;
    for (int i = 0; i < w; ++i) woff += wsum[i];
    int run = woff + x - tsum;
    #pragma unroll
    for (int i = 0; i < 4; ++i) {
        if (base + i < NN) offs[base + i] = run;
        run += v[i];
    }
    if (t == 255) csums[b] = woff + x;
}

__global__ void scan_tops_kernel(int* __restrict__ csums, int* __restrict__ offs, int nchunks) {
    if (threadIdx.x == 0 && blockIdx.x == 0) {
        int run = 0;
        for (int i = 0; i < nchunks; ++i) { int c = csums[i]; csums[i] = run; run += c; }
        offs[NN] = run;
    }
}

__global__ void scan_add_kernel(int* __restrict__ offs, const int* __restrict__ csums) {
    int i = blockIdx.x * blockDim.x + threadIdx.x;
    if (i < NN) offs[i] += csums[i >> 10];
}

// builds eperm (edge -> csr position), srcp and dstp (csr-ordered src/dst)
__global__ void scatter_kernel(const int* __restrict__ dst, const int* __restrict__ src,
                               const int* __restrict__ offs, int* __restrict__ cursor,
                               int* __restrict__ eperm, int* __restrict__ srcp,
                               int* __restrict__ dstp)
{
    int e = blockIdx.x * blockDim.x + threadIdx.x;
    if (e >= NE) return;
    int d = dst[e];
    int pos = offs[d] + atomicAdd(&cursor[d], 1);
    eperm[e] = pos;
    srcp[pos] = src[e];
    dstp[pos] = d;
}

__global__ void gstart_kernel(const int* __restrict__ batch, int* __restrict__ gstart) {
    int n = blockIdx.x * blockDim.x + threadIdx.x;
    if (n > NN) return;
    if (n == NN) {
        for (int g = batch[NN - 1] + 1; g <= NG; ++g) gstart[g] = NN;
        return;
    }
    int b = batch[n];
    int pb = (n == 0) ? -1 : batch[n - 1];
    for (int g = pb + 1; g <= b; ++g) gstart[g] = n;
}

// ---------------- conversions ----------------------------------------------

// ea f32 [E,101] -> bf16 [EP,128] in CSR order; col 101 = 1.0 (bias slot)
__global__ __launch_bounds__(256) void cvt_ea_kernel(const float* __restrict__ ea,
                                                     const int* __restrict__ eperm,
                                                     ushort* __restrict__ eabc)
{
    const int t = threadIdx.x;
    const int r = blockIdx.x * 8 + (t >> 5);
    if (r >= NE) return;
    const int pos = eperm[r];
    const int c = (t & 31) * 4;
    ushort4 o;
    #pragma unroll
    for (int i = 0; i < 4; ++i) {
        const int col = c + i;
        float v = (col < DE) ? ea[(size_t)r * DE + col] : ((col == DE) ? 1.0f : 0.0f);
        ((ushort*)&o)[i] = f2bf(v);
    }
    *(ushort4*)&eabc[(size_t)pos * 128 + c] = o;
}

// in f32 [Kin,Nn] -> out bf16 [Nn][Kp] transposed; row Kin = bias (if given), rest 0
__global__ void cvt_wt_kernel(const float* __restrict__ in, ushort* __restrict__ out,
                              int Kin, int Nn, int Kp, const float* __restrict__ bias)
{
    const int n = blockIdx.x;
    for (int k = threadIdx.x; k < Kp; k += blockDim.x) {
        float v = 0.0f;
        if (k < Kin) v = in[(size_t)k * Nn + n];
        else if (k == Kin && bias) v = bias[n];
        out[(size_t)n * Kp + k] = f2bf(v);
    }
}

// ---------------- fused edge GEMM + segment-sum aggregation ------------------
// r12 structure + ONE change: the FULL per-wave B tile (16 fragments = 16 KB)
// is loaded into registers BEFORE any MFMA. Little's-law fix: per-wave bytes
// in flight go 4 KB -> 16 KB, lifting the latency-bound eabc stream toward BW.
__global__ __launch_bounds__(256, 2) void edge_agg_kernel(
    const ushort* __restrict__ eab, const ushort* __restrict__ Wt,
    const int* __restrict__ srcp, const int* __restrict__ dstp,
    const ushort* __restrict__ hb, float* __restrict__ zf)
{
    __shared__ ushort vals[128 * 128];   // [row][col], col XOR-swizzled by row
    __shared__ int nd[128];              // dst node per tile row
    const int tid = threadIdx.x;
    const int wid = tid >> 6;
    const int msub = wid >> 1, nsl = wid & 1;
    const int lane = tid & 63, l15 = lane & 15, grp = lane >> 4;
    const int n0 = nsl * 64;

    bf16x8 A[4][4];
    #pragma unroll
    for (int nf = 0; nf < 4; ++nf)
        #pragma unroll
        for (int kk = 0; kk < 4; ++kk)
            A[nf][kk] = *(const bf16x8*)(Wt + (size_t)(n0 + nf * 16 + l15) * 128 + kk * 32 + grp * 8);

    const int rcol = tid & 127;   // reduce-phase column
    const int rh   = tid >> 7;    // reduce-phase row half (0/1)

    const int ntiles = EP / 128;  // 4688
    for (int t = blockIdx.x; t < ntiles; t += gridDim.x) {
        const int r0 = t * 128;
        const int m0 = r0 + msub * 64;
        BARRIER_LDS();            // previous tile's reduce done before overwriting LDS
        if (tid < 128) {
            const int rr = r0 + tid;
            nd[tid] = (rr < NE) ? dstp[rr] : NN;
        }
        // --- issue ALL B-tile loads first: 16 x 16B per lane in flight ---
        bf16x8 b[4][4];           // [kk][mf]
        #pragma unroll
        for (int kk = 0; kk < 4; ++kk)
            #pragma unroll
            for (int mf = 0; mf < 4; ++mf)
                b[kk][mf] = *(const bf16x8*)(eab + (size_t)(m0 + mf * 16 + l15) * 128 + kk * 32 + grp * 8);
        // h-gather (overlaps with b loads + MFMA)
        int sp[4];
        #pragma unroll
        for (int mf = 0; mf < 4; ++mf) {
            const int rr = m0 + mf * 16 + l15;
            sp[mf] = (rr < NE) ? srcp[rr] : 0;
        }
        ushort4 hv[4][4];
        #pragma unroll
        for (int mf = 0; mf < 4; ++mf)
            #pragma unroll
            for (int nf = 0; nf < 4; ++nf)
                hv[mf][nf] = *(const ushort4*)&hb[(size_t)sp[mf] * 128 + n0 + nf * 16 + grp * 4];
        // --- MFMAs consume the pre-loaded B tile ---
        f32x4 acc[4][4];
        #pragma unroll
        for (int i = 0; i < 4; ++i)
            #pragma unroll
            for (int j = 0; j < 4; ++j) acc[i][j] = (f32x4){0.f, 0.f, 0.f, 0.f};
        #pragma unroll
        for (int kk = 0; kk < 4; ++kk)
            #pragma unroll
            for (int mf = 0; mf < 4; ++mf)
                #pragma unroll
                for (int nf = 0; nf < 4; ++nf)
                    acc[mf][nf] = __builtin_amdgcn_mfma_f32_16x16x32_bf16(A[nf][kk], b[kk][mf], acc[mf][nf], 0, 0, 0);
        // relu(e + h) -> LDS (swizzled: ushort-index col ^ ((row&7)<<3))
        #pragma unroll
        for (int mf = 0; mf < 4; ++mf) {
            const int row = msub * 64 + mf * 16 + l15;
            const int sw = (row & 7) << 3;
            #pragma unroll
            for (int nf = 0; nf < 4; ++nf) {
                const int col = n0 + nf * 16 + grp * 4;
                ushort4 o;
                o.x = f2bf(fmaxf(acc[mf][nf][0] + bf2f(hv[mf][nf].x), 0.f));
                o.y = f2bf(fmaxf(acc[mf][nf][1] + bf2f(hv[mf][nf].y), 0.f));
                o.z = f2bf(fmaxf(acc[mf][nf][2] + bf2f(hv[mf][nf].z), 0.f));
                o.w = f2bf(fmaxf(acc[mf][nf][3] + bf2f(hv[mf][nf].w), 0.f));
                *(ushort4*)&vals[row * 128 + (col ^ sw)] = o;
            }
        }
        BARRIER_LDS();
        // serial segment reduce down the tile (branches wave-uniform: rows shared)
        float accs = 0.f;
        int cur = nd[rh * 64];
        for (int r = rh * 64; r < rh * 64 + 64; ++r) {
            const int node = nd[r];
            const float v = bf2f(vals[r * 128 + (rcol ^ ((r & 7) << 3))]);
            if (node != cur) {
                if (cur < NN) fadd_atomic(&zf[(size_t)cur * 128 + rcol], accs);
                accs = 0.f; cur = node;
            }
            accs += v;
        }
        if (cur < NN) fadd_atomic(&zf[(size_t)cur * 128 + rcol], accs);
    }
}

// ---------------- weight-stationary MFMA GEMMs ------------------------------

// mlp1: y1 = z@W1 + b1 -> bf16 [NP,256]; z is f32, converted in-register.
// BN column stats accumulated in registers, flushed once per block.
__global__ __launch_bounds__(256, 2) void mlp1_gemm_kernel(
    const float* __restrict__ z, const ushort* __restrict__ Wt,
    const float* __restrict__ bias, ushort* __restrict__ y,
    float* __restrict__ s1, float* __restrict__ sq1)
{
    const int n0 = (threadIdx.x >> 6) * 64;
    const int lane = threadIdx.x & 63, l15 = lane & 15, grp = lane >> 4;
    bf16x8 A[4][4];
    #pragma unroll
    for (int nf = 0; nf < 4; ++nf)
        #pragma unroll
        for (int kk = 0; kk < 4; ++kk)
            A[nf][kk] = *(const bf16x8*)(Wt + (size_t)(n0 + nf * 16 + l15) * 128 + kk * 32 + grp * 8);
    float4 bv[4];
    #pragma unroll
    for (int nf = 0; nf < 4; ++nf) bv[nf] = *(const float4*)&bias[n0 + nf * 16 + grp * 4];

    float sj[4][4] = {}, qj[4][4] = {};

    const int ntiles = NP / 64;   // 1564
    for (int t = blockIdx.x; t < ntiles; t += gridDim.x) {
        const int m0 = t * 64;
        f32x4 acc[4][4];
        #pragma unroll
        for (int i = 0; i < 4; ++i)
            #pragma unroll
            for (int j = 0; j < 4; ++j) acc[i][j] = (f32x4){0.f, 0.f, 0.f, 0.f};
        #pragma unroll
        for (int kk = 0; kk < 4; ++kk) {
            bf16x8 b[4];
            #pragma unroll
            for (int mf = 0; mf < 4; ++mf)
                b[mf] = ld_zfrag(z + (size_t)(m0 + mf * 16 + l15) * 128 + kk * 32 + grp * 8);
            #pragma unroll
            for (int mf = 0; mf < 4; ++mf)
                #pragma unroll
                for (int nf = 0; nf < 4; ++nf)
                    acc[mf][nf] = __builtin_amdgcn_mfma_f32_16x16x32_bf16(A[nf][kk], b[mf], acc[mf][nf], 0, 0, 0);
        }
        #pragma unroll
        for (int mf = 0; mf < 4; ++mf) {
            const int m = m0 + mf * 16 + l15;
            const bool valid = m < NN;
            ushort* rp = &y[(size_t)m * 256 + n0];
            #pragma unroll
            for (int nf = 0; nf < 4; ++nf) {
                ushort4 o;
                o.x = f2bf(acc[mf][nf][0] + bv[nf].x);
                o.y = f2bf(acc[mf][nf][1] + bv[nf].y);
                o.z = f2bf(acc[mf][nf][2] + bv[nf].z);
                o.w = f2bf(acc[mf][nf][3] + bv[nf].w);
                *(ushort4*)&rp[nf * 16 + grp * 4] = o;
                if (valid) {
                    float v0 = bf2f(o.x), v1 = bf2f(o.y), v2 = bf2f(o.z), v3 = bf2f(o.w);
                    sj[nf][0] += v0; qj[nf][0] += v0 * v0;
                    sj[nf][1] += v1; qj[nf][1] += v1 * v1;
                    sj[nf][2] += v2; qj[nf][2] += v2 * v2;
                    sj[nf][3] += v3; qj[nf][3] += v3 * v3;
                }
            }
        }
    }
    #pragma unroll
    for (int nf = 0; nf < 4; ++nf) {
        #pragma unroll
        for (int j = 0; j < 4; ++j) {
            float s = sj[nf][j], q = qj[nf][j];
            #pragma unroll
            for (int off = 1; off < 16; off <<= 1) {
                s += __shfl_xor(s, off, 16);
                q += __shfl_xor(q, off, 16);
            }
            if (l15 == 0) {
                const int col = n0 + nf * 16 + grp * 4 + j;
                fadd_atomic(&s1[col], s);
                fadd_atomic(&sq1[col], q);
            }
        }
    }
}

// mlp2: y2 = y1r@W2 + b2 -> bf16 [NP,128]  (y1r pre-activated in place), K=256
__global__ __launch_bounds__(256, 2) void mlp2_gemm_kernel(
    const ushort* __restrict__ y1, const ushort* __restrict__ Wt,
    const float* __restrict__ bias, ushort* __restrict__ y2)
{
    const int wid = threadIdx.x >> 6;
    const int msub = wid >> 1, nsl = wid & 1;
    const int lane = threadIdx.x & 63, l15 = lane & 15, grp = lane >> 4;
    const int n0 = nsl * 64;
    bf16x8 A[4][8];
    #pragma unroll
    for (int nf = 0; nf < 4; ++nf)
        #pragma unroll
        for (int kk = 0; kk < 8; ++kk)
            A[nf][kk] = *(const bf16x8*)(Wt + (size_t)(n0 + nf * 16 + l15) * 256 + kk * 32 + grp * 8);
    float4 bv[4];
    #pragma unroll
    for (int nf = 0; nf < 4; ++nf) bv[nf] = *(const float4*)&bias[n0 + nf * 16 + grp * 4];

    const int ntiles = NP / 128;   // 782
    for (int t = blockIdx.x; t < ntiles; t += gridDim.x) {
        const int m0 = t * 128 + msub * 64;
        f32x4 acc[4][4];
        #pragma unroll
        for (int i = 0; i < 4; ++i)
            #pragma unroll
            for (int j = 0; j < 4; ++j) acc[i][j] = (f32x4){0.f, 0.f, 0.f, 0.f};
        #pragma unroll
        for (int kk = 0; kk < 8; ++kk) {
            bf16x8 b[4];
            #pragma unroll
            for (int mf = 0; mf < 4; ++mf)
                b[mf] = *(const bf16x8*)(y1 + (size_t)(m0 + mf * 16 + l15) * 256 + kk * 32 + grp * 8);
            #pragma unroll
            for (int mf = 0; mf < 4; ++mf)
                #pragma unroll
                for (int nf = 0; nf < 4; ++nf)
                    acc[mf][nf] = __builtin_amdgcn_mfma_f32_16x16x32_bf16(A[nf][kk], b[mf], acc[mf][nf], 0, 0, 0);
        }
        #pragma unroll
        for (int mf = 0; mf < 4; ++mf) {
            ushort* rp = &y2[(size_t)(m0 + mf * 16 + l15) * 128 + n0];
            #pragma unroll
            for (int nf = 0; nf < 4; ++nf) {
                ushort4 o;
                o.x = f2bf(acc[mf][nf][0] + bv[nf].x);
                o.y = f2bf(acc[mf][nf][1] + bv[nf].y);
                o.z = f2bf(acc[mf][nf][2] + bv[nf].z);
                o.w = f2bf(acc[mf][nf][3] + bv[nf].w);
                *(ushort4*)&rp[nf * 16 + grp * 4] = o;
            }
        }
    }
}

// ---------------- elementwise / stats kernels --------------------------------

// h = bf16(x @ W_emb + b_emb); also zf = f32(h)  (runs once; replaces zinit)
__global__ __launch_bounds__(128) void embed_kernel(
    const float* __restrict__ x, const float* __restrict__ W,
    const float* __restrict__ b, ushort* __restrict__ hb, float* __restrict__ zf)
{
    __shared__ float xs[4][DIN];
    const int n0 = blockIdx.x * 4;
    const int d  = threadIdx.x;
    for (int idx = d; idx < 4 * DIN; idx += 128) {
        int r = idx / DIN, c = idx - r * DIN;
        xs[r][c] = x[(size_t)n0 * DIN + idx];
    }
    __syncthreads();
    float bb = b[d];
    float a0 = bb, a1 = bb, a2 = bb, a3 = bb;
    for (int k = 0; k < DIN; ++k) {
        float w = W[k * DD + d];
        a0 = fmaf(xs[0][k], w, a0);
        a1 = fmaf(xs[1][k], w, a1);
        a2 = fmaf(xs[2][k], w, a2);
        a3 = fmaf(xs[3][k], w, a3);
    }
    ushort u0 = f2bf(a0), u1 = f2bf(a1), u2 = f2bf(a2), u3 = f2bf(a3);
    hb[(size_t)(n0 + 0) * DD + d] = u0;
    hb[(size_t)(n0 + 1) * DD + d] = u1;
    hb[(size_t)(n0 + 2) * DD + d] = u2;
    hb[(size_t)(n0 + 3) * DD + d] = u3;
    zf[(size_t)(n0 + 0) * DD + d] = bf2f(u0);
    zf[(size_t)(n0 + 1) * DD + d] = bf2f(u1);
    zf[(size_t)(n0 + 2) * DD + d] = bf2f(u2);
    zf[(size_t)(n0 + 3) * DD + d] = bf2f(u3);
}

// column sums/sumsq of bf16 [*,128], rows < NN
__global__ __launch_bounds__(256) void colstats128b_kernel(
    const ushort* __restrict__ y, float* __restrict__ s, float* __restrict__ q)
{
    const int t = threadIdx.x;
    const int cs = (t & 31) * 4, rg = t >> 5;
    const int r0 = blockIdx.x * 256;
    float ps0 = 0, ps1 = 0, ps2 = 0, ps3 = 0, pq0 = 0, pq1 = 0, pq2 = 0, pq3 = 0;
    for (int i = rg; i < 256; i += 8) {
        const int r = r0 + i;
        if (r >= NN) break;
        ushort4 u = *(const ushort4*)&y[(size_t)r * 128 + cs];
        float f0 = bf2f(u.x), f1 = bf2f(u.y), f2v = bf2f(u.z), f3 = bf2f(u.w);
        ps0 += f0; pq0 += f0 * f0;
        ps1 += f1; pq1 += f1 * f1;
        ps2 += f2v; pq2 += f2v * f2v;
        ps3 += f3; pq3 += f3 * f3;
    }
    __shared__ float SS[8][128], SQ[8][128];
    SS[rg][cs + 0] = ps0; SS[rg][cs + 1] = ps1; SS[rg][cs + 2] = ps2; SS[rg][cs + 3] = ps3;
    SQ[rg][cs + 0] = pq0; SQ[rg][cs + 1] = pq1; SQ[rg][cs + 2] = pq2; SQ[rg][cs + 3] = pq3;
    __syncthreads();
    if (rg == 0) {
        #pragma unroll
        for (int j = 0; j < 4; ++j) {
            const int c = cs + j;
            float sv = 0, qv = 0;
            #pragma unroll
            for (int g = 0; g < 8; ++g) { sv += SS[g][c]; qv += SQ[g][c]; }
            fadd_atomic(&s[c], sv);
            fadd_atomic(&q[c], qv);
        }
    }
}

__global__ void finalize_kernel(const float* __restrict__ s, const float* __restrict__ sq,
                                const float* __restrict__ g, const float* __restrict__ bb,
                                float* __restrict__ a, float* __restrict__ c,
                                int dim, float invN)
{
    int d = blockIdx.x * blockDim.x + threadIdx.x;
    if (d >= dim) return;
    float m  = s[d] * invN;
    float v  = sq[d] * invN - m * m;
    float rs = rsqrtf(v + 1e-5f);
    float ai = g[d] * rs;
    a[d] = ai;
    c[d] = bb[d] - m * ai;
}

// y1 = bf16(relu(bn1(y1))) in place, rows < NN  (256 cols)
__global__ void bnrelu_bf_kernel(ushort* __restrict__ y, const float* __restrict__ a,
                                 const float* __restrict__ c)
{
    int i = blockIdx.x * blockDim.x + threadIdx.x;
    const int stride = gridDim.x * blockDim.x;
    for (; i < NN * 64; i += stride) {
        const int cb = (i & 63) * 4;
        ushort4 u = *(const ushort4*)&y[(size_t)i * 4];
        const float4 av = *(const float4*)&a[cb];
        const float4 cv = *(const float4*)&c[cb];
        ushort4 o;
        o.x = f2bf(fmaxf(fmaf(bf2f(u.x), av.x, cv.x), 0.f));
        o.y = f2bf(fmaxf(fmaf(bf2f(u.y), av.y, cv.y), 0.f));
        o.z = f2bf(fmaxf(fmaf(bf2f(u.z), av.z, cv.z), 0.f));
        o.w = f2bf(fmaxf(fmaf(bf2f(u.w), av.w, cv.w), 0.f));
        *(ushort4*)&y[(size_t)i * 4] = o;
    }
}

// h = bf16(relu(bn(y2))) in place; also zf = f32(h)  (layer 0; replaces zinit)
__global__ void bnrelu_hb_kernel(ushort* __restrict__ hb, const float* __restrict__ a,
                                 const float* __restrict__ c, float* __restrict__ zf)
{
    int i = blockIdx.x * blockDim.x + threadIdx.x;
    const int stride = gridDim.x * blockDim.x;
    for (; i < NN * 32; i += stride) {
        const int cb = (i & 31) * 4;
        ushort4 u = *(const ushort4*)&hb[(size_t)i * 4];
        const float4 av = *(const float4*)&a[cb];
        const float4 cv = *(const float4*)&c[cb];
        ushort4 o;
        o.x = f2bf(fmaxf(fmaf(bf2f(u.x), av.x, cv.x), 0.f));
        o.y = f2bf(fmaxf(fmaf(bf2f(u.y), av.y, cv.y), 0.f));
        o.z = f2bf(fmaxf(fmaf(bf2f(u.z), av.z, cv.z), 0.f));
        o.w = f2bf(fmaxf(fmaf(bf2f(u.w), av.w, cv.w), 0.f));
        *(ushort4*)&hb[(size_t)i * 4] = o;
        float4 zo;
        zo.x = bf2f(o.x); zo.y = bf2f(o.y); zo.z = bf2f(o.z); zo.w = bf2f(o.w);
        *(float4*)&zf[(size_t)i * 4] = zo;
    }
}

// final: out[g] = bn(mean over node range of y2)  (one wave per graph)
__global__ __launch_bounds__(256) void pool_kernel(
    const ushort* __restrict__ hb, const float* __restrict__ a2, const float* __restrict__ c2,
    const int* __restrict__ gstart, float* __restrict__ out)
{
    const int g = blockIdx.x * 4 + (threadIdx.x >> 6);
    if (g >= NG) return;
    const int lane = threadIdx.x & 63;
    const int s = gstart[g], t = gstart[g + 1];
    float a0 = 0.f, a1 = 0.f;
    for (int n = s; n < t; ++n) {
        const uint v = *(const uint*)&hb[(size_t)n * 128 + lane * 2];
        a0 += __uint_as_float(v << 16);
        a1 += __uint_as_float(v & 0xffff0000u);
    }
    const int d0 = lane * 2;
    float2 o;
    if (t > s) {
        const float inv = 1.0f / (float)(t - s);
        o.x = fmaf(a2[d0 + 0], a0 * inv, c2[d0 + 0]);
        o.y = fmaf(a2[d0 + 1], a1 * inv, c2[d0 + 1]);
    } else {
        o.x = 0.f; o.y = 0.f;
    }
    *(float2*)&out[(size_t)g * 128 + d0] = o;
}

// ---------------- launch ----------------------------------------------------

extern "C" void kernel_launch(void* const* d_in, const int* in_sizes, int n_in,
                              void* d_out, int out_size, void* d_ws, size_t ws_size,
                              hipStream_t stream)
{
    (void)in_sizes; (void)n_in; (void)out_size; (void)ws_size;
    const float* x     = (const float*)d_in[0];
    const float* ea    = (const float*)d_in[1];
    const int*   src   = (const int*)d_in[2];
    const int*   dst   = (const int*)d_in[3];
    const int*   batch = (const int*)d_in[4];
    const float* W_emb = (const float*)d_in[5];
    const float* b_emb = (const float*)d_in[6];

    char* ws = (char*)d_ws;
    auto alloc = [&](size_t bytes) { void* p = ws; ws += (bytes + 255) & ~(size_t)255; return p; };

    ushort* hb   = (ushort*)alloc((size_t)NP * 128 * 2);   // 25.6 MB  h / y2 (bf16)
    float*  zf   = (float*) alloc((size_t)NP * 128 * 4);   // 51.2 MB  z (f32)
    ushort* eabc = (ushort*)alloc((size_t)EP * 128 * 2);   // 153.6 MB ea bf16, CSR order
    ushort* y1b  = (ushort*)alloc((size_t)NP * 256 * 2);   // 51.2 MB  y1 (bf16)
    int* deg    = (int*)alloc((size_t)NN * 4);
    int* offs   = (int*)alloc((size_t)(NN + 1) * 4);
    int* eperm  = (int*)alloc((size_t)NE * 4);
    int* srcp   = (int*)alloc((size_t)NE * 4);
    int* dstp   = (int*)alloc((size_t)NE * 4);
    int* csums  = (int*)alloc(128 * 4);
    int* gstart = (int*)alloc((size_t)(NG + 1) * 4);
    ushort* Wet[2], *W1t[2], *W2t[2];
    for (int l = 0; l < 2; ++l) {
        Wet[l] = (ushort*)alloc(128 * 128 * 2);
        W1t[l] = (ushort*)alloc(256 * 128 * 2);
        W2t[l] = (ushort*)alloc(128 * 256 * 2);
    }
    float* st = (float*)alloc(2048 * 4);
    float* s1 = st,        *sq1 = st + 256, *a1 = st + 512,  *c1 = st + 768;
    float* s2 = st + 1024, *sq2 = st + 1152, *a2 = st + 1280, *c2 = st + 1408;
    float* out = (float*)d_out;

    const int NCHUNK = (NN + 1023) / 1024;

    // CSR + permutation + graph boundaries (constant across layers)
    hipMemsetAsync(deg, 0, (size_t)NN * 4, stream);
    hist_kernel<<<(NE + 255) / 256, 256, 0, stream>>>(dst, deg);
    scan_chunk_kernel<<<NCHUNK, 256, 0, stream>>>(deg, offs, csums);
    scan_tops_kernel<<<1, 1, 0, stream>>>(csums, offs, NCHUNK);
    scan_add_kernel<<<(NN + 255) / 256, 256, 0, stream>>>(offs, csums);
    hipMemsetAsync(deg, 0, (size_t)NN * 4, stream);
    scatter_kernel<<<(NE + 255) / 256, 256, 0, stream>>>(dst, src, offs, deg, eperm, srcp, dstp);
    gstart_kernel<<<(NN + 256) / 256, 256, 0, stream>>>(batch, gstart);

    // one-time conversions (ea goes directly to CSR order, bias slot at col 101)
    cvt_ea_kernel<<<(NE + 7) / 8, 256, 0, stream>>>(ea, eperm, eabc);
    for (int l = 0; l < 2; ++l) {
        const float* const* L = (const float* const*)(d_in + 7 + l * 10);
        cvt_wt_kernel<<<128, 128, 0, stream>>>(L[0], Wet[l], 101, 128, 128, L[1]);  // We + be row
        cvt_wt_kernel<<<256, 128, 0, stream>>>(L[2], W1t[l], 128, 256, 128, nullptr);
        cvt_wt_kernel<<<128, 128, 0, stream>>>(L[6], W2t[l], 256, 128, 256, nullptr);
    }

    embed_kernel<<<NN / 4, 128, 0, stream>>>(x, W_emb, b_emb, hb, zf);

    for (int layer = 0; layer < 2; ++layer) {
        const float* const* L = (const float* const*)(d_in + 7 + layer * 10);
        const float* b1  = L[3];
        const float* g1  = L[4]; const float* bb1 = L[5];
        const float* b2  = L[7];
        const float* go  = L[8]; const float* bo  = L[9];

        hipMemsetAsync(s1, 0, 512 * sizeof(float), stream);   // s1+sq1
        hipMemsetAsync(s2, 0, 256 * sizeof(float), stream);   // s2+sq2

        edge_agg_kernel<<<1172, 256, 0, stream>>>(eabc, Wet[layer], srcp, dstp, hb, zf);

        mlp1_gemm_kernel<<<782, 256, 0, stream>>>(zf, W1t[layer], b1, y1b, s1, sq1);
        finalize_kernel<<<1, 256, 0, stream>>>(s1, sq1, g1, bb1, a1, c1, 256, 1.0f / NN);
        bnrelu_bf_kernel<<<2048, 256, 0, stream>>>(y1b, a1, c1);
        mlp2_gemm_kernel<<<391, 256, 0, stream>>>(y1b, W2t[layer], b2, hb);
        colstats128b_kernel<<<NP / 256 + 1, 256, 0, stream>>>(hb, s2, sq2);
        finalize_kernel<<<1, 128, 0, stream>>>(s2, sq2, go, bo, a2, c2, 128, 1.0f / NN);

        if (layer == 0) {
            bnrelu_hb_kernel<<<2048, 256, 0, stream>>>(hb, a2, c2, zf);
        } else {
            pool_kernel<<<NG / 4, 256, 0, stream>>>(hb, a2, c2, gstart, out);
        }
    }
}